// Round 5
// baseline (550.300 us; speedup 1.0000x reference)
//
#include <hip/hip_runtime.h>
#include <cstdint>
#include <cmath>

#define NH 16
#define HD 64
#define SQ 2048
#define NB 4
#define DM 1024

typedef _Float16 half_t;
typedef _Float16 h8 __attribute__((ext_vector_type(8)));
typedef _Float16 h4 __attribute__((ext_vector_type(4)));
typedef float f4 __attribute__((ext_vector_type(4)));

// bucket(delta) per MT5 relative_position_bucket (bidirectional, 32 buckets, max_dist 128)
__device__ __forceinline__ int rel_bucket(int delta) {
    int b = (delta > 0) ? 16 : 0;
    int a = (delta < 0) ? -delta : delta;
    if (a < 8) return b + a;
    int large = 8 + (int)(__logf((float)a * 0.125f) * 2.8853900817779268f);
    return b + (large < 15 ? large : 15);
}

// async global->LDS, 16B per lane; LDS dest = wave-uniform base + lane*16
__device__ __forceinline__ void gl_lds(const half_t* g, half_t* l) {
    __builtin_amdgcn_global_load_lds((const __attribute__((address_space(1))) unsigned int*)g,
                                     (__attribute__((address_space(3))) unsigned int*)l, 16, 0, 0);
}

// ---- prep: X f32->f16 (blocks 0..4095) + W transposes (blocks 4096..5119) ---
__global__ __launch_bounds__(256) void prep(const float* __restrict__ X,
                                            const float* __restrict__ Wq,
                                            const float* __restrict__ Wk,
                                            const float* __restrict__ Wv,
                                            const float* __restrict__ Wo,
                                            half_t* __restrict__ Xh, half_t* __restrict__ Wqt,
                                            half_t* __restrict__ Wkt, half_t* __restrict__ Wvt,
                                            half_t* __restrict__ Wot) {
    const int id = blockIdx.x;
    if (id < 4096) {
        size_t i = ((size_t)id * 256 + threadIdx.x) * 8;
        float4 a = *(const float4*)&X[i];
        float4 b = *(const float4*)&X[i + 4];
        half_t t[8] = {(half_t)a.x, (half_t)a.y, (half_t)a.z, (half_t)a.w,
                       (half_t)b.x, (half_t)b.y, (half_t)b.z, (half_t)b.w};
        *(h8*)&Xh[i] = *(h8*)t;
        return;
    }
    __shared__ float T[64][65];
    const int t = id - 4096;
    const int which = t >> 8, tile = t & 255;
    const float* W = which == 0 ? Wq : which == 1 ? Wk : which == 2 ? Wv : Wo;
    half_t* Wt = which == 0 ? Wqt : which == 1 ? Wkt : which == 2 ? Wvt : Wot;
    const int k0 = (tile >> 4) * 64, n0 = (tile & 15) * 64;
    const int c = threadIdx.x & 63, rr = threadIdx.x >> 6;
    for (int r = rr; r < 64; r += 4) T[r][c] = W[(size_t)(k0 + r) * DM + n0 + c];
    __syncthreads();
    for (int r = rr; r < 64; r += 4) Wt[(size_t)(n0 + r) * DM + k0 + c] = (half_t)T[c][r];
}

// ---- v[bh][s][d] f16 -> vT[bh][d][s] f16 ------------------------------------
__global__ __launch_bounds__(256) void transpose_v(const half_t* __restrict__ v,
                                                   half_t* __restrict__ vT) {
    __shared__ half_t T[64][72];
    const int bh = blockIdx.y, j0 = blockIdx.x * 64;
    const size_t base = (size_t)bh * (SQ * HD);
    const int t = threadIdx.x;
    for (int e = t; e < 512; e += 256) {
        int r = e >> 3, c = e & 7;
        *(h8*)&T[r][c * 8] = *(const h8*)&v[base + (size_t)(j0 + r) * HD + c * 8];
    }
    __syncthreads();
    const int d = t & 63, jc = t >> 6;
    half_t tmp[16];
#pragma unroll
    for (int jj = 0; jj < 16; ++jj) tmp[jj] = T[jc * 16 + jj][d];
    *(h8*)&vT[base + (size_t)d * SQ + j0 + jc * 16] = *(h8*)&tmp[0];
    *(h8*)&vT[base + (size_t)d * SQ + j0 + jc * 16 + 8] = *(h8*)&tmp[8];
}

// ---- QKV MFMA GEMM: dbuf LDS, 1 barrier/K-step; z selects W/out -------------
__global__ __launch_bounds__(256) void mm_qkv(const half_t* __restrict__ A,
                                              const half_t* __restrict__ Wqt,
                                              const half_t* __restrict__ Wkt,
                                              const half_t* __restrict__ Wvt,
                                              half_t* __restrict__ qo, half_t* __restrict__ ko,
                                              half_t* __restrict__ vo) {
    const int z = blockIdx.z;
    const half_t* Bt = z == 0 ? Wqt : z == 1 ? Wkt : Wvt;
    half_t* outp = z == 0 ? qo : z == 1 ? ko : vo;
    __shared__ half_t Al[2][4096];
    __shared__ half_t Bl[2][4096];
    const int tid = threadIdx.x;
    const int lane = tid & 63, w = tid >> 6;
    const int wr = w >> 1, wc = w & 1;
    const int m0 = blockIdx.y * 128, n0 = blockIdx.x * 128;

    f4 acc[4][4];
#pragma unroll
    for (int i = 0; i < 4; ++i)
#pragma unroll
        for (int j = 0; j < 4; ++j) acc[i][j] = (f4){0.f, 0.f, 0.f, 0.f};

    const int kc = lane >> 4;
    const int srl = lane >> 2;
    const int sc = lane & 3;

    auto stage = [&](int buf, int k0) {
#pragma unroll
        for (int inst = 0; inst < 2; ++inst) {
            int r = w * 32 + inst * 16 + srl;
            int cg = sc ^ ((r >> 1) & 3);
            gl_lds(&A[(size_t)(m0 + r) * DM + k0 + cg * 8], &Al[buf][(w * 32 + inst * 16) * 32]);
            gl_lds(&Bt[(size_t)(n0 + r) * DM + k0 + cg * 8], &Bl[buf][(w * 32 + inst * 16) * 32]);
        }
    };

    stage(0, 0);
    __syncthreads();
    int cur = 0;
    for (int t = 0; t < 32; ++t) {
        if (t < 31) stage(cur ^ 1, (t + 1) * 32);
        h8 af[4], bf[4];
#pragma unroll
        for (int ms = 0; ms < 4; ++ms) {
            int r = wr * 64 + ms * 16 + (lane & 15);
            af[ms] = *(const h8*)&Al[cur][r * 32 + ((kc ^ ((r >> 1) & 3)) * 8)];
        }
#pragma unroll
        for (int ns = 0; ns < 4; ++ns) {
            int r = wc * 64 + ns * 16 + (lane & 15);
            bf[ns] = *(const h8*)&Bl[cur][r * 32 + ((kc ^ ((r >> 1) & 3)) * 8)];
        }
#pragma unroll
        for (int ms = 0; ms < 4; ++ms)
#pragma unroll
            for (int ns = 0; ns < 4; ++ns)
                acc[ms][ns] =
                    __builtin_amdgcn_mfma_f32_16x16x32_f16(af[ms], bf[ns], acc[ms][ns], 0, 0, 0);
        __syncthreads();
        cur ^= 1;
    }

#pragma unroll
    for (int ms = 0; ms < 4; ++ms)
#pragma unroll
        for (int ns = 0; ns < 4; ++ns)
#pragma unroll
            for (int reg = 0; reg < 4; ++reg) {
                int m = m0 + wr * 64 + ms * 16 + (lane >> 4) * 4 + reg;
                int n = n0 + wc * 64 + ns * 16 + (lane & 15);
                int b = m >> 11, s = m & 2047, h = n >> 6, d = n & 63;
                outp[((size_t)(b * NH + h) * SQ + s) * HD + d] = (half_t)acc[ms][ns][reg];
            }
}

// ---- Wo GEMM: dbuf LDS, f32 nt row-major out --------------------------------
__global__ __launch_bounds__(256) void mm_wo(const half_t* __restrict__ A,
                                             const half_t* __restrict__ Bt,
                                             float* __restrict__ outp) {
    __shared__ half_t Al[2][4096];
    __shared__ half_t Bl[2][4096];
    const int tid = threadIdx.x;
    const int lane = tid & 63, w = tid >> 6;
    const int wr = w >> 1, wc = w & 1;
    const int m0 = blockIdx.y * 128, n0 = blockIdx.x * 128;

    f4 acc[4][4];
#pragma unroll
    for (int i = 0; i < 4; ++i)
#pragma unroll
        for (int j = 0; j < 4; ++j) acc[i][j] = (f4){0.f, 0.f, 0.f, 0.f};

    const int kc = lane >> 4;
    const int srl = lane >> 2;
    const int sc = lane & 3;

    auto stage = [&](int buf, int k0) {
#pragma unroll
        for (int inst = 0; inst < 2; ++inst) {
            int r = w * 32 + inst * 16 + srl;
            int cg = sc ^ ((r >> 1) & 3);
            gl_lds(&A[(size_t)(m0 + r) * DM + k0 + cg * 8], &Al[buf][(w * 32 + inst * 16) * 32]);
            gl_lds(&Bt[(size_t)(n0 + r) * DM + k0 + cg * 8], &Bl[buf][(w * 32 + inst * 16) * 32]);
        }
    };

    stage(0, 0);
    __syncthreads();
    int cur = 0;
    for (int t = 0; t < 32; ++t) {
        if (t < 31) stage(cur ^ 1, (t + 1) * 32);
        h8 af[4], bf[4];
#pragma unroll
        for (int ms = 0; ms < 4; ++ms) {
            int r = wr * 64 + ms * 16 + (lane & 15);
            af[ms] = *(const h8*)&Al[cur][r * 32 + ((kc ^ ((r >> 1) & 3)) * 8)];
        }
#pragma unroll
        for (int ns = 0; ns < 4; ++ns) {
            int r = wc * 64 + ns * 16 + (lane & 15);
            bf[ns] = *(const h8*)&Bl[cur][r * 32 + ((kc ^ ((r >> 1) & 3)) * 8)];
        }
#pragma unroll
        for (int ms = 0; ms < 4; ++ms)
#pragma unroll
            for (int ns = 0; ns < 4; ++ns)
                acc[ms][ns] =
                    __builtin_amdgcn_mfma_f32_16x16x32_f16(af[ms], bf[ns], acc[ms][ns], 0, 0, 0);
        __syncthreads();
        cur ^= 1;
    }

#pragma unroll
    for (int ms = 0; ms < 4; ++ms)
#pragma unroll
        for (int ns = 0; ns < 4; ++ns)
#pragma unroll
            for (int reg = 0; reg < 4; ++reg) {
                int m = m0 + wr * 64 + ms * 16 + (lane >> 4) * 4 + reg;
                int n = n0 + wc * 64 + ns * 16 + (lane & 15);
                __builtin_nontemporal_store(acc[ms][ns][reg], &outp[(size_t)m * DM + n]);
            }
}

// ---- fused attention: swapped QK^T, 2-pass, dbuf K/V, counted-vmcnt barrier -
// block = 128 q-rows of one (b,h); 4 waves x 32 rows. C-frag reg dim = j.
__global__ __launch_bounds__(256) void fused_attn(const half_t* __restrict__ q,
                                                  const half_t* __restrict__ k,
                                                  const half_t* __restrict__ vT,
                                                  const float* __restrict__ table,
                                                  float* __restrict__ attw,
                                                  half_t* __restrict__ ctx) {
    __shared__ float biasE[2176];     // exp(bias(delta)), u = j - (i - i0) + 127
    __shared__ char Psm[16384];       // per-wave 4KB: P[32 i][64 j] f16, 16B-slot XOR swizzle
    __shared__ half_t Kl[2][4096];    // K tile dbuf: row j x 64 d; slot s of row r = chunk s^(r&7)
    __shared__ half_t Vl[2][4096];    // V^T tile dbuf: row d x 64 j; same swizzle
    const int tid = threadIdx.x, lane = tid & 63, w = tid >> 6;

    // XCD-bijective swizzle: each bh's 16 blocks on one XCD
    const int id = blockIdx.x;
    const int idx = (id & 7) * 128 + (id >> 3);
    const int bh = idx >> 4, i0 = (idx & 15) * 128;
    const int h = bh & 15, b = bh >> 4;
    const size_t qb = (size_t)bh * (SQ * HD);
    const half_t* kb = k + qb;
    const half_t* vb = vT + qb;

    for (int t = tid; t < 2176; t += 256)
        biasE[t] = __expf(table[rel_bucket(t - i0 - 127) * NH + h]);

    h8 qf[2][2];
#pragma unroll
    for (int isub = 0; isub < 2; ++isub) {
        const half_t* qp =
            &q[qb + (size_t)(i0 + w * 32 + isub * 16 + (lane & 15)) * HD + (lane >> 4) * 8];
        qf[isub][0] = *(const h8*)qp;
        qf[isub][1] = *(const h8*)(qp + 32);
    }

    const int sr = lane >> 3;  // staging row within 8-row group
    const int sc = lane & 7;   // LDS slot

    auto stageK = [&](int buf, int j0) {
#pragma unroll
        for (int inst = 0; inst < 2; ++inst) {
            int r = w * 16 + inst * 8 + sr;
            gl_lds(&kb[(size_t)(j0 + r) * HD + ((sc ^ (r & 7)) * 8)],
                   &Kl[buf][(w * 16 + inst * 8) * 64]);
        }
    };
    auto stageV = [&](int buf, int j0) {
#pragma unroll
        for (int inst = 0; inst < 2; ++inst) {
            int r = w * 16 + inst * 8 + sr;
            gl_lds(&vb[(size_t)r * SQ + j0 + ((sc ^ (r & 7)) * 8)],
                   &Vl[buf][(w * 16 + inst * 8) * 64]);
        }
    };

    // ---- pass 1: row sums of exp(score)*exp(bias), K dbuf -------------------
    stageK(0, 0);
    __syncthreads();  // covers biasE + stage
    float srow[2] = {0.f, 0.f};
    int cur = 0;
    for (int t = 0; t < 32; ++t) {
        const int j0 = t * 64;
        if (t < 31) stageK(cur ^ 1, j0 + 64);
#pragma unroll
        for (int ns = 0; ns < 4; ++ns) {
            const int rr = ns * 16 + (lane & 15);
            const int kc = lane >> 4;
            h8 kf0 = *(const h8*)&Kl[cur][rr * 64 + ((kc ^ (rr & 7)) * 8)];
            h8 kf1 = *(const h8*)&Kl[cur][rr * 64 + (((kc + 4) ^ (rr & 7)) * 8)];
#pragma unroll
            for (int isub = 0; isub < 2; ++isub) {
                f4 z = (f4){0.f, 0.f, 0.f, 0.f};
                z = __builtin_amdgcn_mfma_f32_16x16x32_f16(kf0, qf[isub][0], z, 0, 0, 0);
                z = __builtin_amdgcn_mfma_f32_16x16x32_f16(kf1, qf[isub][1], z, 0, 0, 0);
                int u0 =
                    j0 + ns * 16 + ((lane >> 4) << 2) - (w * 32 + isub * 16 + (lane & 15)) + 127;
#pragma unroll
                for (int reg = 0; reg < 4; ++reg)
                    srow[isub] = fmaf(__expf(z[reg]), biasE[u0 + reg], srow[isub]);
            }
        }
        __syncthreads();
        cur ^= 1;
    }
    float sinv[2];
#pragma unroll
    for (int isub = 0; isub < 2; ++isub) {
        float s = srow[isub];
        s += __shfl_xor(s, 16);
        s += __shfl_xor(s, 32);
        sinv[isub] = 1.0f / s;
    }

    // ---- pass 2: recompute, nt float4 attw writes, PV; counted-vmcnt barrier
    f4 o[4][2];
#pragma unroll
    for (int ns = 0; ns < 4; ++ns)
#pragma unroll
        for (int isub = 0; isub < 2; ++isub) o[ns][isub] = (f4){0.f, 0.f, 0.f, 0.f};
    const size_t awb = (size_t)bh * ((size_t)SQ * SQ);
    char* Pw = Psm + w * 4096;

    stageK(0, 0);
    stageV(0, 0);
    __syncthreads();
    cur = 0;
    for (int t = 0; t < 32; ++t) {
        const int j0 = t * 64;
        if (t < 31) {
            stageK(cur ^ 1, j0 + 64);
            stageV(cur ^ 1, j0 + 64);
        }
        __builtin_amdgcn_sched_barrier(0);  // pin: staging loads issue before attw stores
        f4 a[4][2];
#pragma unroll
        for (int ns = 0; ns < 4; ++ns) {
            const int rr = ns * 16 + (lane & 15);
            const int kc = lane >> 4;
            h8 kf0 = *(const h8*)&Kl[cur][rr * 64 + ((kc ^ (rr & 7)) * 8)];
            h8 kf1 = *(const h8*)&Kl[cur][rr * 64 + (((kc + 4) ^ (rr & 7)) * 8)];
#pragma unroll
            for (int isub = 0; isub < 2; ++isub) {
                f4 z = (f4){0.f, 0.f, 0.f, 0.f};
                z = __builtin_amdgcn_mfma_f32_16x16x32_f16(kf0, qf[isub][0], z, 0, 0, 0);
                z = __builtin_amdgcn_mfma_f32_16x16x32_f16(kf1, qf[isub][1], z, 0, 0, 0);
                a[ns][isub] = z;
            }
        }
#pragma unroll
        for (int ns = 0; ns < 4; ++ns)
#pragma unroll
            for (int isub = 0; isub < 2; ++isub) {
                const int wloc = w * 32 + isub * 16 + (lane & 15);
                const int jbase = ns * 16 + ((lane >> 4) << 2);
                const int u0 = j0 + jbase - wloc + 127;
                f4 p;
#pragma unroll
                for (int reg = 0; reg < 4; ++reg)
                    p[reg] = __expf(a[ns][isub][reg]) * biasE[u0 + reg] * sinv[isub];
                __builtin_nontemporal_store(p,
                                            (f4*)&attw[awb + (size_t)(i0 + wloc) * SQ + j0 + jbase]);
                const int iloc = isub * 16 + (lane & 15);
                h4 ph = {(half_t)p[0], (half_t)p[1], (half_t)p[2], (half_t)p[3]};
                *(h4*)&Pw[iloc * 128 + (((jbase >> 3) ^ (iloc & 7)) << 4) + ((jbase & 4) << 1)] = ph;
            }
        h8 pf[2][2];
#pragma unroll
        for (int isub = 0; isub < 2; ++isub) {
            const int iloc = isub * 16 + (lane & 15);
            pf[isub][0] = *(const h8*)&Pw[iloc * 128 + (((lane >> 4) ^ (iloc & 7)) << 4)];
            pf[isub][1] = *(const h8*)&Pw[iloc * 128 + ((((lane >> 4) + 4) ^ (iloc & 7)) << 4)];
        }
#pragma unroll
        for (int ns = 0; ns < 4; ++ns) {
            const int rr = ns * 16 + (lane & 15);
            const int kc = lane >> 4;
            h8 vf0 = *(const h8*)&Vl[cur][rr * 64 + ((kc ^ (rr & 7)) * 8)];
            h8 vf1 = *(const h8*)&Vl[cur][rr * 64 + (((kc + 4) ^ (rr & 7)) * 8)];
#pragma unroll
            for (int isub = 0; isub < 2; ++isub) {
                o[ns][isub] =
                    __builtin_amdgcn_mfma_f32_16x16x32_f16(pf[isub][0], vf0, o[ns][isub], 0, 0, 0);
                o[ns][isub] =
                    __builtin_amdgcn_mfma_f32_16x16x32_f16(pf[isub][1], vf1, o[ns][isub], 0, 0, 0);
            }
        }
        // counted wait: 4 staging loads are the oldest vmem ops of this iter;
        // the 8 nt attw stores issued after them are allowed to stay in flight.
        asm volatile("s_waitcnt vmcnt(8)" ::: "memory");
        __builtin_amdgcn_s_barrier();
        __builtin_amdgcn_sched_barrier(0);
        cur ^= 1;
    }
#pragma unroll
    for (int ns = 0; ns < 4; ++ns)
#pragma unroll
        for (int isub = 0; isub < 2; ++isub)
#pragma unroll
            for (int reg = 0; reg < 4; ++reg) {
                int row = i0 + w * 32 + isub * 16 + (lane >> 4) * 4 + reg;
                int d = ns * 16 + (lane & 15);
                ctx[((size_t)(b * SQ + row)) * DM + h * HD + d] = (half_t)o[ns][isub][reg];
            }
}

// ---- position_bias fill: pb[h,i,j] = table[bucket(j-i), h] (nt) -------------
__global__ __launch_bounds__(256) void bias_fill(const float* __restrict__ table,
                                                 float* __restrict__ pb) {
    __shared__ float t[512];
    const int tid = threadIdx.x;
    t[tid] = table[tid];
    t[tid + 256] = table[tid + 256];
    __syncthreads();
    const int i = blockIdx.x;
    const int h = blockIdx.y;
    const size_t base = ((size_t)h * SQ + i) * SQ;
#pragma unroll
    for (int half = 0; half < 2; ++half) {
        int j = half * 1024 + tid * 4;
        f4 o;
        o[0] = t[rel_bucket(j + 0 - i) * NH + h];
        o[1] = t[rel_bucket(j + 1 - i) * NH + h];
        o[2] = t[rel_bucket(j + 2 - i) * NH + h];
        o[3] = t[rel_bucket(j + 3 - i) * NH + h];
        __builtin_nontemporal_store(o, (f4*)&pb[base + j]);
    }
}

extern "C" void kernel_launch(void* const* d_in, const int* in_sizes, int n_in, void* d_out,
                              int out_size, void* d_ws, size_t ws_size, hipStream_t stream) {
    const float* X = (const float*)d_in[0];
    const float* Wq = (const float*)d_in[1];
    const float* Wk = (const float*)d_in[2];
    const float* Wv = (const float*)d_in[3];
    const float* Wo = (const float*)d_in[4];
    const float* tbl = (const float*)d_in[5];

    float* out = (float*)d_out;
    float* attn_out = out;                    // 8,388,608 f32
    float* pb = out + (size_t)NB * SQ * DM;   // 67,108,864 f32
    float* attw = pb + (size_t)NH * SQ * SQ;  // 268,435,456 f32

    // f16 scratch: prefer d_ws; fall back to pb region (bias_fill overwrites LAST)
    const size_t need_bytes = 109051904;  // 54,525,952 halfs
    half_t* hb = (ws_size >= need_bytes) ? (half_t*)d_ws : (half_t*)pb;
    half_t* Xh = hb;
    half_t* qh = hb + 8388608;
    half_t* kh = hb + 16777216;
    half_t* vh = hb + 25165824;
    half_t* vTh = hb + 33554432;
    half_t* ctxh = hb + 41943040;
    half_t* Wqt = hb + 50331648;
    half_t* Wkt = hb + 51380224;
    half_t* Wvt = hb + 52428800;
    half_t* Wot = hb + 53477376;

    dim3 blk(256);
    prep<<<dim3(5120), blk, 0, stream>>>(X, Wq, Wk, Wv, Wo, Xh, Wqt, Wkt, Wvt, Wot);
    mm_qkv<<<dim3(8, 64, 3), blk, 0, stream>>>(Xh, Wqt, Wkt, Wvt, qh, kh, vh);
    transpose_v<<<dim3(32, 64), blk, 0, stream>>>(vh, vTh);
    fused_attn<<<dim3(1024), blk, 0, stream>>>(qh, kh, vTh, tbl, attw, ctxh);
    mm_wo<<<dim3(8, 64), blk, 0, stream>>>(ctxh, Wot, attn_out);
    bias_fill<<<dim3(SQ, NH), blk, 0, stream>>>(tbl, pb);
}

// Round 6
// 542.634 us; speedup vs baseline: 1.0141x; 1.0141x over previous
//
#include <hip/hip_runtime.h>
#include <cstdint>
#include <cmath>

#define NH 16
#define HD 64
#define SQ 2048
#define NB 4
#define DM 1024

typedef _Float16 half_t;
typedef _Float16 h8 __attribute__((ext_vector_type(8)));
typedef _Float16 h4 __attribute__((ext_vector_type(4)));
typedef float f4 __attribute__((ext_vector_type(4)));

// bucket(delta) per MT5 relative_position_bucket (bidirectional, 32 buckets, max_dist 128)
__device__ __forceinline__ int rel_bucket(int delta) {
    int b = (delta > 0) ? 16 : 0;
    int a = (delta < 0) ? -delta : delta;
    if (a < 8) return b + a;
    int large = 8 + (int)(__logf((float)a * 0.125f) * 2.8853900817779268f);
    return b + (large < 15 ? large : 15);
}

// async global->LDS, 16B per lane; LDS dest = wave-uniform base + lane*16
__device__ __forceinline__ void gl_lds(const half_t* g, half_t* l) {
    __builtin_amdgcn_global_load_lds((const __attribute__((address_space(1))) unsigned int*)g,
                                     (__attribute__((address_space(3))) unsigned int*)l, 16, 0, 0);
}

// ---- prep: X f32->f16 (blocks 0..4095) + W transposes (4096..5119)
//      + delta-table build (5120..5135) ---------------------------------------
__global__ __launch_bounds__(256) void prep(const float* __restrict__ X,
                                            const float* __restrict__ Wq,
                                            const float* __restrict__ Wk,
                                            const float* __restrict__ Wv,
                                            const float* __restrict__ Wo,
                                            const float* __restrict__ table,
                                            half_t* __restrict__ Xh, half_t* __restrict__ Wqt,
                                            half_t* __restrict__ Wkt, half_t* __restrict__ Wvt,
                                            half_t* __restrict__ Wot, float* __restrict__ dtab) {
    const int id = blockIdx.x;
    if (id < 4096) {
        size_t i = ((size_t)id * 256 + threadIdx.x) * 8;
        float4 a = *(const float4*)&X[i];
        float4 b = *(const float4*)&X[i + 4];
        half_t t[8] = {(half_t)a.x, (half_t)a.y, (half_t)a.z, (half_t)a.w,
                       (half_t)b.x, (half_t)b.y, (half_t)b.z, (half_t)b.w};
        *(h8*)&Xh[i] = *(h8*)t;
        return;
    }
    if (id >= 5120) {
        const int h = id - 5120;  // dtab[h][d] = bias(delta = d - 2047) for head h
        for (int d = threadIdx.x; d < 4095; d += 256)
            dtab[h * 4096 + d] = table[rel_bucket(d - 2047) * NH + h];
        return;
    }
    __shared__ float T[64][65];
    const int t = id - 4096;
    const int which = t >> 8, tile = t & 255;
    const float* W = which == 0 ? Wq : which == 1 ? Wk : which == 2 ? Wv : Wo;
    half_t* Wt = which == 0 ? Wqt : which == 1 ? Wkt : which == 2 ? Wvt : Wot;
    const int k0 = (tile >> 4) * 64, n0 = (tile & 15) * 64;
    const int c = threadIdx.x & 63, rr = threadIdx.x >> 6;
    for (int r = rr; r < 64; r += 4) T[r][c] = W[(size_t)(k0 + r) * DM + n0 + c];
    __syncthreads();
    for (int r = rr; r < 64; r += 4) Wt[(size_t)(n0 + r) * DM + k0 + c] = (half_t)T[c][r];
}

// ---- v[bh][s][d] f16 -> vT[bh][d][s] f16 ------------------------------------
__global__ __launch_bounds__(256) void transpose_v(const half_t* __restrict__ v,
                                                   half_t* __restrict__ vT) {
    __shared__ half_t T[64][72];
    const int bh = blockIdx.y, j0 = blockIdx.x * 64;
    const size_t base = (size_t)bh * (SQ * HD);
    const int t = threadIdx.x;
    for (int e = t; e < 512; e += 256) {
        int r = e >> 3, c = e & 7;
        *(h8*)&T[r][c * 8] = *(const h8*)&v[base + (size_t)(j0 + r) * HD + c * 8];
    }
    __syncthreads();
    const int d = t & 63, jc = t >> 6;
    half_t tmp[16];
#pragma unroll
    for (int jj = 0; jj < 16; ++jj) tmp[jj] = T[jc * 16 + jj][d];
    *(h8*)&vT[base + (size_t)d * SQ + j0 + jc * 16] = *(h8*)&tmp[0];
    *(h8*)&vT[base + (size_t)d * SQ + j0 + jc * 16 + 8] = *(h8*)&tmp[8];
}

// ---- QKV MFMA GEMM: dbuf LDS, swapped-operand epilogue (reg dim = n) --------
__global__ __launch_bounds__(256) void mm_qkv(const half_t* __restrict__ A,
                                              const half_t* __restrict__ Wqt,
                                              const half_t* __restrict__ Wkt,
                                              const half_t* __restrict__ Wvt,
                                              half_t* __restrict__ qo, half_t* __restrict__ ko,
                                              half_t* __restrict__ vo) {
    const int z = blockIdx.z;
    const half_t* Bt = z == 0 ? Wqt : z == 1 ? Wkt : Wvt;
    half_t* outp = z == 0 ? qo : z == 1 ? ko : vo;
    __shared__ half_t Al[2][4096];
    __shared__ half_t Bl[2][4096];
    const int tid = threadIdx.x;
    const int lane = tid & 63, w = tid >> 6;
    const int wr = w >> 1, wc = w & 1;
    // XCD-bijective chunk swizzle over 512 blocks (512 % 8 == 0)
    const int id0 = blockIdx.y * 8 + blockIdx.x;
    const int swz = (id0 & 7) * 64 + (id0 >> 3);
    const int m0 = (swz >> 3) * 128, n0 = (swz & 7) * 128;

    f4 acc[4][4];
#pragma unroll
    for (int i = 0; i < 4; ++i)
#pragma unroll
        for (int j = 0; j < 4; ++j) acc[i][j] = (f4){0.f, 0.f, 0.f, 0.f};

    const int kc = lane >> 4;
    const int srl = lane >> 2;
    const int sc = lane & 3;

    auto stage = [&](int buf, int k0) {
#pragma unroll
        for (int inst = 0; inst < 2; ++inst) {
            int r = w * 32 + inst * 16 + srl;
            int cg = sc ^ ((r >> 1) & 3);
            gl_lds(&A[(size_t)(m0 + r) * DM + k0 + cg * 8], &Al[buf][(w * 32 + inst * 16) * 32]);
            gl_lds(&Bt[(size_t)(n0 + r) * DM + k0 + cg * 8], &Bl[buf][(w * 32 + inst * 16) * 32]);
        }
    };

    stage(0, 0);
    __syncthreads();
    int cur = 0;
    for (int t = 0; t < 32; ++t) {
        if (t < 31) stage(cur ^ 1, (t + 1) * 32);
        h8 af[4], bf[4];
#pragma unroll
        for (int ms = 0; ms < 4; ++ms) {
            int r = wr * 64 + ms * 16 + (lane & 15);
            af[ms] = *(const h8*)&Al[cur][r * 32 + ((kc ^ ((r >> 1) & 3)) * 8)];
        }
#pragma unroll
        for (int ns = 0; ns < 4; ++ns) {
            int r = wc * 64 + ns * 16 + (lane & 15);
            bf[ns] = *(const h8*)&Bl[cur][r * 32 + ((kc ^ ((r >> 1) & 3)) * 8)];
        }
        // swapped operands: C col (lane&15) = m, reg dim = n
#pragma unroll
        for (int ms = 0; ms < 4; ++ms)
#pragma unroll
            for (int ns = 0; ns < 4; ++ns)
                acc[ms][ns] =
                    __builtin_amdgcn_mfma_f32_16x16x32_f16(bf[ns], af[ms], acc[ms][ns], 0, 0, 0);
        __syncthreads();
        cur ^= 1;
    }

#pragma unroll
    for (int ms = 0; ms < 4; ++ms)
#pragma unroll
        for (int ns = 0; ns < 4; ++ns) {
            int m = m0 + wr * 64 + ms * 16 + (lane & 15);
            int nb = n0 + wc * 64 + ns * 16 + ((lane >> 4) << 2);
            int b = m >> 11, s = m & 2047, h = nb >> 6, d = nb & 63;
            h4 ph = {(half_t)acc[ms][ns][0], (half_t)acc[ms][ns][1], (half_t)acc[ms][ns][2],
                     (half_t)acc[ms][ns][3]};
            *(h4*)&outp[((size_t)(b * NH + h) * SQ + s) * HD + d] = ph;
        }
}

// ---- Wo GEMM: dbuf LDS, swapped-operand epilogue, f4 nt stores --------------
__global__ __launch_bounds__(256) void mm_wo(const half_t* __restrict__ A,
                                             const half_t* __restrict__ Bt,
                                             float* __restrict__ outp) {
    __shared__ half_t Al[2][4096];
    __shared__ half_t Bl[2][4096];
    const int tid = threadIdx.x;
    const int lane = tid & 63, w = tid >> 6;
    const int wr = w >> 1, wc = w & 1;
    const int id0 = blockIdx.y * 8 + blockIdx.x;
    const int swz = (id0 & 7) * 64 + (id0 >> 3);
    const int m0 = (swz >> 3) * 128, n0 = (swz & 7) * 128;

    f4 acc[4][4];
#pragma unroll
    for (int i = 0; i < 4; ++i)
#pragma unroll
        for (int j = 0; j < 4; ++j) acc[i][j] = (f4){0.f, 0.f, 0.f, 0.f};

    const int kc = lane >> 4;
    const int srl = lane >> 2;
    const int sc = lane & 3;

    auto stage = [&](int buf, int k0) {
#pragma unroll
        for (int inst = 0; inst < 2; ++inst) {
            int r = w * 32 + inst * 16 + srl;
            int cg = sc ^ ((r >> 1) & 3);
            gl_lds(&A[(size_t)(m0 + r) * DM + k0 + cg * 8], &Al[buf][(w * 32 + inst * 16) * 32]);
            gl_lds(&Bt[(size_t)(n0 + r) * DM + k0 + cg * 8], &Bl[buf][(w * 32 + inst * 16) * 32]);
        }
    };

    stage(0, 0);
    __syncthreads();
    int cur = 0;
    for (int t = 0; t < 32; ++t) {
        if (t < 31) stage(cur ^ 1, (t + 1) * 32);
        h8 af[4], bf[4];
#pragma unroll
        for (int ms = 0; ms < 4; ++ms) {
            int r = wr * 64 + ms * 16 + (lane & 15);
            af[ms] = *(const h8*)&Al[cur][r * 32 + ((kc ^ ((r >> 1) & 3)) * 8)];
        }
#pragma unroll
        for (int ns = 0; ns < 4; ++ns) {
            int r = wc * 64 + ns * 16 + (lane & 15);
            bf[ns] = *(const h8*)&Bl[cur][r * 32 + ((kc ^ ((r >> 1) & 3)) * 8)];
        }
#pragma unroll
        for (int ms = 0; ms < 4; ++ms)
#pragma unroll
            for (int ns = 0; ns < 4; ++ns)
                acc[ms][ns] =
                    __builtin_amdgcn_mfma_f32_16x16x32_f16(bf[ns], af[ms], acc[ms][ns], 0, 0, 0);
        __syncthreads();
        cur ^= 1;
    }

#pragma unroll
    for (int ms = 0; ms < 4; ++ms)
#pragma unroll
        for (int ns = 0; ns < 4; ++ns) {
            int m = m0 + wr * 64 + ms * 16 + (lane & 15);
            int nb = n0 + wc * 64 + ns * 16 + ((lane >> 4) << 2);
            __builtin_nontemporal_store(acc[ms][ns], (f4*)&outp[(size_t)m * DM + nb]);
        }
}

// ---- fused attention: swapped QK^T, 2-pass, dbuf K/V, counted-vmcnt barrier -
__global__ __launch_bounds__(256) void fused_attn(const half_t* __restrict__ q,
                                                  const half_t* __restrict__ k,
                                                  const half_t* __restrict__ vT,
                                                  const float* __restrict__ table,
                                                  float* __restrict__ attw,
                                                  half_t* __restrict__ ctx) {
    __shared__ float biasE[2176];     // exp(bias(delta)), u = j - (i - i0) + 127
    __shared__ char Psm[16384];       // per-wave 4KB: P[32 i][64 j] f16, 16B-slot XOR swizzle
    __shared__ half_t Kl[2][4096];    // K tile dbuf
    __shared__ half_t Vl[2][4096];    // V^T tile dbuf
    const int tid = threadIdx.x, lane = tid & 63, w = tid >> 6;

    const int id = blockIdx.x;
    const int idx = (id & 7) * 128 + (id >> 3);
    const int bh = idx >> 4, i0 = (idx & 15) * 128;
    const int h = bh & 15, b = bh >> 4;
    const size_t qb = (size_t)bh * (SQ * HD);
    const half_t* kb = k + qb;
    const half_t* vb = vT + qb;

    for (int t = tid; t < 2176; t += 256)
        biasE[t] = __expf(table[rel_bucket(t - i0 - 127) * NH + h]);

    h8 qf[2][2];
#pragma unroll
    for (int isub = 0; isub < 2; ++isub) {
        const half_t* qp =
            &q[qb + (size_t)(i0 + w * 32 + isub * 16 + (lane & 15)) * HD + (lane >> 4) * 8];
        qf[isub][0] = *(const h8*)qp;
        qf[isub][1] = *(const h8*)(qp + 32);
    }

    const int sr = lane >> 3;
    const int sc = lane & 7;

    auto stageK = [&](int buf, int j0) {
#pragma unroll
        for (int inst = 0; inst < 2; ++inst) {
            int r = w * 16 + inst * 8 + sr;
            gl_lds(&kb[(size_t)(j0 + r) * HD + ((sc ^ (r & 7)) * 8)],
                   &Kl[buf][(w * 16 + inst * 8) * 64]);
        }
    };
    auto stageV = [&](int buf, int j0) {
#pragma unroll
        for (int inst = 0; inst < 2; ++inst) {
            int r = w * 16 + inst * 8 + sr;
            gl_lds(&vb[(size_t)r * SQ + j0 + ((sc ^ (r & 7)) * 8)],
                   &Vl[buf][(w * 16 + inst * 8) * 64]);
        }
    };

    // ---- pass 1 -------------------------------------------------------------
    stageK(0, 0);
    __syncthreads();
    float srow[2] = {0.f, 0.f};
    int cur = 0;
    for (int t = 0; t < 32; ++t) {
        const int j0 = t * 64;
        if (t < 31) stageK(cur ^ 1, j0 + 64);
#pragma unroll
        for (int ns = 0; ns < 4; ++ns) {
            const int rr = ns * 16 + (lane & 15);
            const int kc = lane >> 4;
            h8 kf0 = *(const h8*)&Kl[cur][rr * 64 + ((kc ^ (rr & 7)) * 8)];
            h8 kf1 = *(const h8*)&Kl[cur][rr * 64 + (((kc + 4) ^ (rr & 7)) * 8)];
#pragma unroll
            for (int isub = 0; isub < 2; ++isub) {
                f4 z = (f4){0.f, 0.f, 0.f, 0.f};
                z = __builtin_amdgcn_mfma_f32_16x16x32_f16(kf0, qf[isub][0], z, 0, 0, 0);
                z = __builtin_amdgcn_mfma_f32_16x16x32_f16(kf1, qf[isub][1], z, 0, 0, 0);
                int u0 =
                    j0 + ns * 16 + ((lane >> 4) << 2) - (w * 32 + isub * 16 + (lane & 15)) + 127;
#pragma unroll
                for (int reg = 0; reg < 4; ++reg)
                    srow[isub] = fmaf(__expf(z[reg]), biasE[u0 + reg], srow[isub]);
            }
        }
        __syncthreads();
        cur ^= 1;
    }
    float sinv[2];
#pragma unroll
    for (int isub = 0; isub < 2; ++isub) {
        float s = srow[isub];
        s += __shfl_xor(s, 16);
        s += __shfl_xor(s, 32);
        sinv[isub] = 1.0f / s;
    }

    // ---- pass 2 -------------------------------------------------------------
    f4 o[4][2];
#pragma unroll
    for (int ns = 0; ns < 4; ++ns)
#pragma unroll
        for (int isub = 0; isub < 2; ++isub) o[ns][isub] = (f4){0.f, 0.f, 0.f, 0.f};
    const size_t awb = (size_t)bh * ((size_t)SQ * SQ);
    char* Pw = Psm + w * 4096;

    stageK(0, 0);
    stageV(0, 0);
    __syncthreads();
    cur = 0;
    for (int t = 0; t < 32; ++t) {
        const int j0 = t * 64;
        if (t < 31) {
            stageK(cur ^ 1, j0 + 64);
            stageV(cur ^ 1, j0 + 64);
        }
        __builtin_amdgcn_sched_barrier(0);  // pin: staging loads issue before attw stores
        f4 a[4][2];
#pragma unroll
        for (int ns = 0; ns < 4; ++ns) {
            const int rr = ns * 16 + (lane & 15);
            const int kc = lane >> 4;
            h8 kf0 = *(const h8*)&Kl[cur][rr * 64 + ((kc ^ (rr & 7)) * 8)];
            h8 kf1 = *(const h8*)&Kl[cur][rr * 64 + (((kc + 4) ^ (rr & 7)) * 8)];
#pragma unroll
            for (int isub = 0; isub < 2; ++isub) {
                f4 z = (f4){0.f, 0.f, 0.f, 0.f};
                z = __builtin_amdgcn_mfma_f32_16x16x32_f16(kf0, qf[isub][0], z, 0, 0, 0);
                z = __builtin_amdgcn_mfma_f32_16x16x32_f16(kf1, qf[isub][1], z, 0, 0, 0);
                a[ns][isub] = z;
            }
        }
#pragma unroll
        for (int ns = 0; ns < 4; ++ns)
#pragma unroll
            for (int isub = 0; isub < 2; ++isub) {
                const int wloc = w * 32 + isub * 16 + (lane & 15);
                const int jbase = ns * 16 + ((lane >> 4) << 2);
                const int u0 = j0 + jbase - wloc + 127;
                f4 p;
#pragma unroll
                for (int reg = 0; reg < 4; ++reg)
                    p[reg] = __expf(a[ns][isub][reg]) * biasE[u0 + reg] * sinv[isub];
                __builtin_nontemporal_store(p,
                                            (f4*)&attw[awb + (size_t)(i0 + wloc) * SQ + j0 + jbase]);
                const int iloc = isub * 16 + (lane & 15);
                h4 ph = {(half_t)p[0], (half_t)p[1], (half_t)p[2], (half_t)p[3]};
                *(h4*)&Pw[iloc * 128 + (((jbase >> 3) ^ (iloc & 7)) << 4) + ((jbase & 4) << 1)] = ph;
            }
        h8 pf[2][2];
#pragma unroll
        for (int isub = 0; isub < 2; ++isub) {
            const int iloc = isub * 16 + (lane & 15);
            pf[isub][0] = *(const h8*)&Pw[iloc * 128 + (((lane >> 4) ^ (iloc & 7)) << 4)];
            pf[isub][1] = *(const h8*)&Pw[iloc * 128 + ((((lane >> 4) + 4) ^ (iloc & 7)) << 4)];
        }
#pragma unroll
        for (int ns = 0; ns < 4; ++ns) {
            const int rr = ns * 16 + (lane & 15);
            const int kc = lane >> 4;
            h8 vf0 = *(const h8*)&Vl[cur][rr * 64 + ((kc ^ (rr & 7)) * 8)];
            h8 vf1 = *(const h8*)&Vl[cur][rr * 64 + (((kc + 4) ^ (rr & 7)) * 8)];
#pragma unroll
            for (int isub = 0; isub < 2; ++isub) {
                o[ns][isub] =
                    __builtin_amdgcn_mfma_f32_16x16x32_f16(pf[isub][0], vf0, o[ns][isub], 0, 0, 0);
                o[ns][isub] =
                    __builtin_amdgcn_mfma_f32_16x16x32_f16(pf[isub][1], vf1, o[ns][isub], 0, 0, 0);
            }
        }
        asm volatile("s_waitcnt vmcnt(8)" ::: "memory");
        __builtin_amdgcn_s_barrier();
        __builtin_amdgcn_sched_barrier(0);
        cur ^= 1;
    }
#pragma unroll
    for (int ns = 0; ns < 4; ++ns)
#pragma unroll
        for (int isub = 0; isub < 2; ++isub)
#pragma unroll
            for (int reg = 0; reg < 4; ++reg) {
                int row = i0 + w * 32 + isub * 16 + (lane >> 4) * 4 + reg;
                int d = ns * 16 + (lane & 15);
                ctx[((size_t)(b * SQ + row)) * DM + h * HD + d] = (half_t)o[ns][isub][reg];
            }
}

// ---- position_bias fill: pure streaming from delta table --------------------
__global__ __launch_bounds__(256) void bias_fill(const float* __restrict__ dtab,
                                                 float* __restrict__ pb) {
    __shared__ float L[2052];
    const int i = blockIdx.x, h = blockIdx.y;
    const int s0 = 2047 - i, a0 = s0 & ~3, sh = s0 - a0;
    for (int t = threadIdx.x * 4; t < 2052; t += 1024)
        *(f4*)&L[t] = *(const f4*)&dtab[h * 4096 + a0 + t];
    __syncthreads();
    const size_t base = ((size_t)h * SQ + i) * SQ;
#pragma unroll
    for (int half = 0; half < 2; ++half) {
        int j = half * 1024 + threadIdx.x * 4;
        f4 o = {L[sh + j], L[sh + j + 1], L[sh + j + 2], L[sh + j + 3]};
        __builtin_nontemporal_store(o, (f4*)&pb[base + j]);
    }
}

extern "C" void kernel_launch(void* const* d_in, const int* in_sizes, int n_in, void* d_out,
                              int out_size, void* d_ws, size_t ws_size, hipStream_t stream) {
    const float* X = (const float*)d_in[0];
    const float* Wq = (const float*)d_in[1];
    const float* Wk = (const float*)d_in[2];
    const float* Wv = (const float*)d_in[3];
    const float* Wo = (const float*)d_in[4];
    const float* tbl = (const float*)d_in[5];

    float* out = (float*)d_out;
    float* attn_out = out;                    // 8,388,608 f32
    float* pb = out + (size_t)NB * SQ * DM;   // 67,108,864 f32
    float* attw = pb + (size_t)NH * SQ * SQ;  // 268,435,456 f32

    // f16 scratch: prefer d_ws; fall back to pb region (bias_fill overwrites LAST)
    const size_t need_bytes = 109314048;  // 54,525,952 halfs + 65,536 f32 dtab
    half_t* hb = (ws_size >= need_bytes) ? (half_t*)d_ws : (half_t*)pb;
    half_t* Xh = hb;
    half_t* qh = hb + 8388608;
    half_t* kh = hb + 16777216;
    half_t* vh = hb + 25165824;
    half_t* vTh = hb + 33554432;
    half_t* ctxh = hb + 41943040;
    half_t* Wqt = hb + 50331648;
    half_t* Wkt = hb + 51380224;
    half_t* Wvt = hb + 52428800;
    half_t* Wot = hb + 53477376;
    float* dtab = (float*)(hb + 54525952);  // 16 x 4096 f32

    dim3 blk(256);
    prep<<<dim3(5136), blk, 0, stream>>>(X, Wq, Wk, Wv, Wo, tbl, Xh, Wqt, Wkt, Wvt, Wot, dtab);
    mm_qkv<<<dim3(8, 64, 3), blk, 0, stream>>>(Xh, Wqt, Wkt, Wvt, qh, kh, vh);
    transpose_v<<<dim3(32, 64), blk, 0, stream>>>(vh, vTh);
    fused_attn<<<dim3(1024), blk, 0, stream>>>(qh, kh, vTh, tbl, attw, ctxh);
    mm_wo<<<dim3(8, 64), blk, 0, stream>>>(ctxh, Wot, attn_out);
    bias_fill<<<dim3(SQ, NH), blk, 0, stream>>>(dtab, pb);
}